// Round 22
// baseline (216.518 us; speedup 1.0000x reference)
//
#include <hip/hip_runtime.h>
#include <math.h>

#define N_USER 100000
#define N_ITEM 50000
#define N_EDGE 800000
#define D_IN 256
#define D_H 128
#define HEADS 4

typedef __attribute__((ext_vector_type(8))) _Float16 half8v;  // 8 f16 (4 VGPR)
typedef __attribute__((ext_vector_type(4))) float f32x4;      // 4 fp32

__device__ __forceinline__ unsigned short f2bf(float x) {    // RNE f32->bf16
  unsigned u = __float_as_uint(x);
  return (unsigned short)((u + 0x7FFFu + ((u >> 16) & 1u)) >> 16);
}
__device__ __forceinline__ float bf2f(unsigned short h) {
  return __uint_as_float((unsigned)h << 16);
}
__device__ __forceinline__ f32x4 splat4(float x) { return (f32x4){x, x, x, x}; }

// ---------------------------------------------------------------------------
// CSR row offsets, edge-parallel run writes (each rs[i] written exactly once).
// ---------------------------------------------------------------------------
__global__ void row_offsets_kernel(const int* __restrict__ dst, int n_edge,
                                   int* __restrict__ rs, int n_dst) {
  int e = blockIdx.x * blockDim.x + threadIdx.x;
  if (e >= n_edge) return;
  int d = dst[e];
  int dprev = (e == 0) ? -1 : dst[e - 1];
  for (int i = dprev + 1; i <= d; ++i) rs[i] = e;
  if (e == n_edge - 1)
    for (int i = d + 1; i <= n_dst; ++i) rs[i] = n_edge;
}

// ---------------------------------------------------------------------------
// One-time W prep: W[256][128] fp32 -> Wt[128][256] fp16, k permuted to MFMA
// slot order: pos(k) s.t. slot (kb,j) holds k = kb*4 + (j&3) + 16*(j>>2).
// ---------------------------------------------------------------------------
__global__ __launch_bounds__(256) void wt_prep_kernel(
    const float* __restrict__ W, _Float16* __restrict__ Wt) {
  int tid = blockIdx.x * blockDim.x + threadIdx.x;
  if (tid >= D_IN * D_H) return;
  int n = tid & 127, k = tid >> 7;
  float x = W[(size_t)k * D_H + n];
  int kk = k & 31, kbase = k & ~31;
  int pos = (kk < 16) ? ((kk >> 2) * 8 + (kk & 3))
                      : (((kk - 16) >> 2) * 8 + 4 + (kk & 3));
  Wt[(size_t)n * D_IN + kbase + pos] = (_Float16)x;
}

// ---------------------------------------------------------------------------
// Stage one K-step tile (A fp32 128x32 swizzled + B fp16 128x32) into LDS
// entirely via global_load_lds DMA. 6 gll instructions per wave.
// ---------------------------------------------------------------------------
__device__ __forceinline__ void stage_tile(
    const float* __restrict__ A, const _Float16* __restrict__ Wt,
    int m0, int M, int k0, int wave, int lane, float* Af, _Float16* Bf) {
#pragma unroll
  for (int i = 0; i < 4; ++i) {
    int rloc = wave * 32 + i * 8 + (lane >> 3);
    int gr = m0 + rloc; if (gr >= M) gr = M - 1;       // clamp; rows never stored
    int u = (lane & 7) ^ (rloc & 7);
    const float* src = A + (size_t)gr * D_IN + k0 + u * 4;
    char* dstb = (char*)Af + (size_t)(wave * 32 + i * 8) * 128;  // wave-uniform
    __builtin_amdgcn_global_load_lds(
        (const __attribute__((address_space(1))) unsigned int*)src,
        (__attribute__((address_space(3))) unsigned int*)dstb, 16, 0, 0);
  }
  // B: fp16 row = 64B; lane l -> row base+(l>>2), 16B unit l&3 (linear).
#pragma unroll
  for (int i = 0; i < 2; ++i) {
    int row = wave * 32 + i * 16 + (lane >> 2);
    int ch = lane & 3;
    const _Float16* srch = Wt + (size_t)row * D_IN + k0 + ch * 8;
    char* dsth = (char*)Bf + (size_t)(wave * 32 + i * 16) * 64;
    __builtin_amdgcn_global_load_lds(
        (const __attribute__((address_space(1))) unsigned int*)srch,
        (__attribute__((address_space(3))) unsigned int*)dsth, 16, 0, 0);
  }
}

// ---------------------------------------------------------------------------
// FUSED fp16 projections + FUSED SCORES (r21-exact GEMM, banked at ~94us).
// Triple-buffer depth-2 counted-vmcnt pipeline.
// C/D layout (verified m89): col = lane&15, row = (lane>>4)*4 + reg.
// ---------------------------------------------------------------------------
__global__ __launch_bounds__(256) void gemm_fused_kernel(
    const float* __restrict__ Au, const float* __restrict__ Ai,
    const _Float16* __restrict__ WtU, const _Float16* __restrict__ WtI,
    const float* __restrict__ bu, const float* __restrict__ bi,
    const float* __restrict__ aUdst, const float* __restrict__ aUsrc,
    const float* __restrict__ aIdst,
    float* __restrict__ sUdst, float* __restrict__ sIsrc,
    float* __restrict__ sIdst,
    unsigned short* __restrict__ CiBf, int nbu) {
  __shared__ float Af[3][128 * 32];                     // 3 x 16KB
  __shared__ _Float16 Bfs[3][128 * 32];                 // 3 x 8KB  (total 72KB)
  const bool isU = (int)blockIdx.x < nbu;
  const float* A = isU ? Au : Ai;
  const _Float16* Wt = isU ? WtU : WtI;
  const float* bias = isU ? bu : bi;
  const int M = isU ? N_USER : N_ITEM;
  const int m0 = (isU ? (int)blockIdx.x : (int)blockIdx.x - nbu) * 128;

  const int t = threadIdx.x;
  const int wave = t >> 6, lane = t & 63;
  const int l15 = lane & 15, kb = lane >> 4;

  f32x4 acc[2][8];
#pragma unroll
  for (int mf = 0; mf < 2; ++mf)
#pragma unroll
    for (int nf = 0; nf < 8; ++nf) acc[mf][nf] = (f32x4){0.f, 0.f, 0.f, 0.f};

  stage_tile(A, Wt, m0, M, 0, wave, lane, Af[0], Bfs[0]);
  stage_tile(A, Wt, m0, M, 32, wave, lane, Af[1], Bfs[1]);

#pragma unroll
  for (int ts = 0; ts < 8; ++ts) {
    const int cur = ts % 3;
    if (ts + 2 < 8) {                                  // prefetch tile ts+2
      stage_tile(A, Wt, m0, M, (ts + 2) * 32, wave, lane,
                 Af[(ts + 2) % 3], Bfs[(ts + 2) % 3]);
      asm volatile("s_waitcnt vmcnt(12)" ::: "memory"); // ts done; ts+1,ts+2 fly
    } else if (ts == 6) {
      asm volatile("s_waitcnt vmcnt(6)" ::: "memory");  // ts=6 done; 7 in flight
    } else {
      asm volatile("s_waitcnt vmcnt(0)" ::: "memory");  // final tile: drain all
    }
    __builtin_amdgcn_sched_barrier(0);                 // rule #18 fence
    __builtin_amdgcn_s_barrier();                      // all waves' tile ts ready

    half8v ah[2];
#pragma unroll
    for (int mf = 0; mf < 2; ++mf) {
      int row = wave * 32 + mf * 16 + l15;
      int u0 = kb ^ (row & 7);
      int u1 = (kb + 4) ^ (row & 7);
      float4 f0 = *(const float4*)((const char*)Af[cur] + (size_t)row * 128 + u0 * 16);
      float4 f1 = *(const float4*)((const char*)Af[cur] + (size_t)row * 128 + u1 * 16);
      const float e[8] = {f0.x, f0.y, f0.z, f0.w, f1.x, f1.y, f1.z, f1.w};
#pragma unroll
      for (int j = 0; j < 8; ++j) ah[mf][j] = (_Float16)e[j];
    }
#pragma unroll
    for (int nf = 0; nf < 8; ++nf) {
      half8v bh = *(const half8v*)((const char*)Bfs[cur] + (size_t)(nf * 16 + l15) * 64 + kb * 16);
#pragma unroll
      for (int mf = 0; mf < 2; ++mf)
        acc[mf][nf] = __builtin_amdgcn_mfma_f32_16x16x32_f16(ah[mf], bh, acc[mf][nf], 0, 0, 0);
    }
    __builtin_amdgcn_s_barrier();   // readers done before buf reuse (no drain)
  }

  // ---- epilogue: bf16 C (item) + fused scores ----
  if (!isU) {
#pragma unroll
    for (int nf = 0; nf < 8; ++nf) {
      float b8 = bias[nf * 16 + l15];
#pragma unroll
      for (int mf = 0; mf < 2; ++mf) {
#pragma unroll
        for (int r = 0; r < 4; ++r) {
          int grow = m0 + wave * 32 + mf * 16 + kb * 4 + r;
          if (grow < M)
            CiBf[(size_t)grow * D_H + nf * 16 + l15] = f2bf(acc[mf][nf][r] + b8);
        }
      }
    }
  }
  const float* a0 = isU ? aUdst : aUsrc;
  float* s0 = isU ? sUdst : sIsrc;
#pragma unroll
  for (int h = 0; h < HEADS; ++h) {
    float a0v[8], bd0 = 0.f;
#pragma unroll
    for (int nf = 0; nf < 8; ++nf) {
      a0v[nf] = a0[h * D_H + nf * 16 + l15];
      bd0 = fmaf(bias[nf * 16 + l15], a0v[nf], bd0);
    }
#pragma unroll
    for (int mf = 0; mf < 2; ++mf) {
#pragma unroll
      for (int r = 0; r < 4; ++r) {
        float p = bd0;
#pragma unroll
        for (int nf = 0; nf < 8; ++nf) p = fmaf(acc[mf][nf][r], a0v[nf], p);
        p += __shfl_xor(p, 1); p += __shfl_xor(p, 2);
        p += __shfl_xor(p, 4); p += __shfl_xor(p, 8);
        int grow = m0 + wave * 32 + mf * 16 + kb * 4 + r;
        if (l15 == 0 && grow < M) s0[grow * HEADS + h] = p;
      }
    }
  }
  if (!isU) {
#pragma unroll
    for (int h = 0; h < HEADS; ++h) {
      float a1v[8], bd1 = 0.f;
#pragma unroll
      for (int nf = 0; nf < 8; ++nf) {
        a1v[nf] = aIdst[h * D_H + nf * 16 + l15];
        bd1 = fmaf(bias[nf * 16 + l15], a1v[nf], bd1);
      }
#pragma unroll
      for (int mf = 0; mf < 2; ++mf) {
#pragma unroll
        for (int r = 0; r < 4; ++r) {
          float p = bd1;
#pragma unroll
          for (int nf = 0; nf < 8; ++nf) p = fmaf(acc[mf][nf][r], a1v[nf], p);
          p += __shfl_xor(p, 1); p += __shfl_xor(p, 2);
          p += __shfl_xor(p, 4); p += __shfl_xor(p, 8);
          int grow = m0 + wave * 32 + mf * 16 + kb * 4 + r;
          if (l15 == 0 && grow < M) sIdst[grow * HEADS + h] = p;
        }
      }
    }
  }
}

// ---------------------------------------------------------------------------
// Weighted gather-sum with inline edge weights, 4-EDGE MLP (r22): 4 gather
// rows + 4 score vectors issued before any FMA -> 16 cache lines in flight
// per half-wave (was 8). Accumulation order identical to r18 (bit-exact).
// 2 dst/wave, bf16 gather rows; den lane-uniform.
// ---------------------------------------------------------------------------
__global__ __launch_bounds__(256) void attend_sum_kernel(
    const unsigned short* __restrict__ h_src, const float* __restrict__ s_src,
    const float* __restrict__ s_dst, const int* __restrict__ src_idx,
    const int* __restrict__ rs, float* __restrict__ out,
    unsigned short* __restrict__ out_bf, int n_dst,
    const float* __restrict__ a_next, float* __restrict__ s_out) {
  int gw = (blockIdx.x * blockDim.x + threadIdx.x) >> 6;   // global wave id
  int lane = threadIdx.x & 63;
  int half = lane >> 5;
  int ll = lane & 31;                // dim group: dims [ll*4, ll*4+4)
  int wid = gw * 2 + half;           // this half's dst node
  if (wid >= n_dst) return;
  int e0 = rs[wid], e1 = rs[wid + 1];
  f32x4 sd = *(const f32x4*)&s_dst[(size_t)wid * HEADS];

#define EDGE_W(sv, wv) {                                                    \
    f32x4 v_ = sv + sd;                                                     \
    v_.x = (v_.x >= 0.f) ? v_.x : 0.2f * v_.x;                              \
    v_.y = (v_.y >= 0.f) ? v_.y : 0.2f * v_.y;                              \
    v_.z = (v_.z >= 0.f) ? v_.z : 0.2f * v_.z;                              \
    v_.w = (v_.w >= 0.f) ? v_.w : 0.2f * v_.w;                              \
    wv = (f32x4){__expf(v_.x), __expf(v_.y), __expf(v_.z), __expf(v_.w)};   \
  }
#define ACCUM(wv, hv) {                                                     \
    den += wv;                                                              \
    acc0 = __builtin_elementwise_fma(splat4(wv.x), hv, acc0);               \
    acc1 = __builtin_elementwise_fma(splat4(wv.y), hv, acc1);               \
    acc2 = __builtin_elementwise_fma(splat4(wv.z), hv, acc2);               \
    acc3 = __builtin_elementwise_fma(splat4(wv.w), hv, acc3);               \
  }

  f32x4 acc0 = {0, 0, 0, 0}, acc1 = acc0, acc2 = acc0, acc3 = acc0;
  f32x4 den = {0, 0, 0, 0};

  int base = e0;
  for (; base + 4 <= e1; base += 4) {          // 4 edges in flight
    int sA = src_idx[base],     sB = src_idx[base + 1];
    int sC = src_idx[base + 2], sD = src_idx[base + 3];
    ushort4 gA = *(const ushort4*)&h_src[(size_t)sA * D_H + ll * 4];
    ushort4 gB = *(const ushort4*)&h_src[(size_t)sB * D_H + ll * 4];
    ushort4 gC = *(const ushort4*)&h_src[(size_t)sC * D_H + ll * 4];
    ushort4 gD = *(const ushort4*)&h_src[(size_t)sD * D_H + ll * 4];
    f32x4 svA = *(const f32x4*)&s_src[(size_t)sA * HEADS];
    f32x4 svB = *(const f32x4*)&s_src[(size_t)sB * HEADS];
    f32x4 svC = *(const f32x4*)&s_src[(size_t)sC * HEADS];
    f32x4 svD = *(const f32x4*)&s_src[(size_t)sD * HEADS];
    f32x4 hA = {bf2f(gA.x), bf2f(gA.y), bf2f(gA.z), bf2f(gA.w)};
    f32x4 hB = {bf2f(gB.x), bf2f(gB.y), bf2f(gB.z), bf2f(gB.w)};
    f32x4 hC = {bf2f(gC.x), bf2f(gC.y), bf2f(gC.z), bf2f(gC.w)};
    f32x4 hD = {bf2f(gD.x), bf2f(gD.y), bf2f(gD.z), bf2f(gD.w)};
    f32x4 wA, wB, wC, wD;
    EDGE_W(svA, wA); EDGE_W(svB, wB); EDGE_W(svC, wC); EDGE_W(svD, wD);
    ACCUM(wA, hA); ACCUM(wB, hB); ACCUM(wC, hC); ACCUM(wD, hD);
  }
  for (; base + 2 <= e1; base += 2) {          // 2-edge tail
    int sA = src_idx[base], sB = src_idx[base + 1];
    ushort4 gA = *(const ushort4*)&h_src[(size_t)sA * D_H + ll * 4];
    ushort4 gB = *(const ushort4*)&h_src[(size_t)sB * D_H + ll * 4];
    f32x4 svA = *(const f32x4*)&s_src[(size_t)sA * HEADS];
    f32x4 svB = *(const f32x4*)&s_src[(size_t)sB * HEADS];
    f32x4 hA = {bf2f(gA.x), bf2f(gA.y), bf2f(gA.z), bf2f(gA.w)};
    f32x4 hB = {bf2f(gB.x), bf2f(gB.y), bf2f(gB.z), bf2f(gB.w)};
    f32x4 wA, wB;
    EDGE_W(svA, wA); EDGE_W(svB, wB);
    ACCUM(wA, hA); ACCUM(wB, hB);
  }
  if (base < e1) {                             // 1-edge tail
    int s = src_idx[base];
    ushort4 gv = *(const ushort4*)&h_src[(size_t)s * D_H + ll * 4];
    f32x4 sv = *(const f32x4*)&s_src[(size_t)s * HEADS];
    f32x4 hv = {bf2f(gv.x), bf2f(gv.y), bf2f(gv.z), bf2f(gv.w)};
    f32x4 wv;
    EDGE_W(sv, wv);
    ACCUM(wv, hv);
  }
#undef EDGE_W
#undef ACCUM

  float rA = den.x > 0.f ? __builtin_amdgcn_rcpf(den.x) : 0.f;
  float rB = den.y > 0.f ? __builtin_amdgcn_rcpf(den.y) : 0.f;
  float rC = den.z > 0.f ? __builtin_amdgcn_rcpf(den.z) : 0.f;
  float rD = den.w > 0.f ? __builtin_amdgcn_rcpf(den.w) : 0.f;
  acc0 *= splat4(rA); acc1 *= splat4(rB); acc2 *= splat4(rC); acc3 *= splat4(rD);
#define ELU4(a) \
  a.x = (a.x > 0.f) ? a.x : (__expf(a.x) - 1.f); \
  a.y = (a.y > 0.f) ? a.y : (__expf(a.y) - 1.f); \
  a.z = (a.z > 0.f) ? a.z : (__expf(a.z) - 1.f); \
  a.w = (a.w > 0.f) ? a.w : (__expf(a.w) - 1.f);
  ELU4(acc0) ELU4(acc1) ELU4(acc2) ELU4(acc3)
#undef ELU4
  f32x4 o = (acc0 + acc1 + acc2 + acc3) * splat4(0.25f);
  *(f32x4*)&out[(size_t)wid * D_H + ll * 4] = o;
  if (out_bf) {
    ushort4 ob = {f2bf(o.x), f2bf(o.y), f2bf(o.z), f2bf(o.w)};
    *(ushort4*)&out_bf[(size_t)wid * D_H + ll * 4] = ob;
  }

  if (s_out) {
#pragma unroll
    for (int h = 0; h < HEADS; ++h) {
      const float* ah = &a_next[h * D_H + ll * 4];
      float p = o.x * ah[0] + o.y * ah[1] + o.z * ah[2] + o.w * ah[3];
#pragma unroll
      for (int off = 16; off; off >>= 1) p += __shfl_xor(p, off);
      if (ll == 0) s_out[wid * HEADS + h] = p;
    }
  }
}

// ---------------------------------------------------------------------------
extern "C" void kernel_launch(void* const* d_in, const int* in_sizes, int n_in,
                              void* d_out, int out_size, void* d_ws, size_t ws_size,
                              hipStream_t stream) {
  const float* h_user     = (const float*)d_in[0];
  const float* h_item     = (const float*)d_in[1];
  const float* w_user     = (const float*)d_in[2];
  const float* b_user     = (const float*)d_in[3];
  const float* w_item     = (const float*)d_in[4];
  const float* b_item     = (const float*)d_in[5];
  const float* a_user_src = (const float*)d_in[6];
  const float* a_user_dst = (const float*)d_in[7];
  const float* a_item_src = (const float*)d_in[8];
  const float* a_item_dst = (const float*)d_in[9];
  const int* i2u_src = (const int*)d_in[10];
  const int* i2u_dst = (const int*)d_in[11];
  const int* u2i_src = (const int*)d_in[12];
  const int* u2i_dst = (const int*)d_in[13];

  float* out_user = (float*)d_out;                       // hu_new (N_USER,128)
  float* out_item = out_user + (size_t)N_USER * D_H;     // hi_new (N_ITEM,128)

  // workspace layout
  float* base_f  = (float*)d_ws;
  unsigned short* ou_bf = (unsigned short*)base_f;       // (N_USER,128) bf16 25.6MB
  float* s_i_src = (float*)(ou_bf + (size_t)N_USER * D_H);  // (N_ITEM,4)
  float* s_i_dst = s_i_src + (size_t)N_ITEM * HEADS;     // (N_ITEM,4)
  float* s_u_dst = s_i_dst + (size_t)N_ITEM * HEADS;     // (N_USER,4)
  float* s_un    = s_u_dst + (size_t)N_USER * HEADS;     // (N_USER,4)
  int* user_rs = (int*)(s_un + (size_t)N_USER * HEADS);  // N_USER+1
  int* item_rs = user_rs + (N_USER + 1);                 // N_ITEM+1
  _Float16* wtu = (_Float16*)
      (((uintptr_t)(item_rs + N_ITEM + 1) + 15) & ~(uintptr_t)15);
  _Float16* wti = wtu + (size_t)D_IN * D_H;              // 64KB each
  unsigned short* hi_bf = (unsigned short*)(wti + (size_t)D_IN * D_H);  // 12.8MB

  // CSR offsets (edge-parallel run writes)
  hipLaunchKernelGGL(row_offsets_kernel, dim3((N_EDGE + 255) / 256), dim3(256), 0,
                     stream, i2u_dst, N_EDGE, user_rs, N_USER);
  hipLaunchKernelGGL(row_offsets_kernel, dim3((N_EDGE + 255) / 256), dim3(256), 0,
                     stream, u2i_dst, N_EDGE, item_rs, N_ITEM);

  // W prep + FUSED fp16 projections+scores (one dispatch, 1173 blocks)
  hipLaunchKernelGGL(wt_prep_kernel, dim3(D_IN * D_H / 256), dim3(256), 0, stream,
                     w_user, wtu);
  hipLaunchKernelGGL(wt_prep_kernel, dim3(D_IN * D_H / 256), dim3(256), 0, stream,
                     w_item, wti);
  const int nbu = (N_USER + 127) / 128;                  // 782
  const int nbi = (N_ITEM + 127) / 128;                  // 391
  hipLaunchKernelGGL(gemm_fused_kernel, dim3(nbu + nbi), dim3(256), 0, stream,
                     h_user, h_item, wtu, wti, b_user, b_item,
                     a_user_dst, a_user_src, a_item_dst,
                     s_u_dst, s_i_src, s_i_dst, hi_bf, nbu);

  // ---- layer 1: items -> users ----  (bf16 gather; inline edge weights)
  hipLaunchKernelGGL(attend_sum_kernel, dim3((N_USER + 7) / 8), dim3(256), 0, stream,
                     hi_bf, s_i_src, s_u_dst, i2u_src, user_rs,
                     out_user, ou_bf, N_USER, a_item_src, s_un);

  // ---- layer 2: updated users -> items ----
  hipLaunchKernelGGL(attend_sum_kernel, dim3((N_ITEM + 7) / 8), dim3(256), 0, stream,
                     ou_bf, s_un, s_i_dst, u2i_src, item_rs,
                     out_item, (unsigned short*)nullptr, N_ITEM,
                     (const float*)nullptr, (float*)nullptr);
}

// Round 23
// 205.388 us; speedup vs baseline: 1.0542x; 1.0542x over previous
//
#include <hip/hip_runtime.h>
#include <math.h>

#define N_USER 100000
#define N_ITEM 50000
#define N_EDGE 800000
#define D_IN 256
#define D_H 128
#define HEADS 4

typedef __attribute__((ext_vector_type(8))) _Float16 half8v;  // 8 f16 (4 VGPR)
typedef __attribute__((ext_vector_type(4))) float f32x4;      // 4 fp32

__device__ __forceinline__ unsigned short f2bf(float x) {    // RNE f32->bf16
  unsigned u = __float_as_uint(x);
  return (unsigned short)((u + 0x7FFFu + ((u >> 16) & 1u)) >> 16);
}
__device__ __forceinline__ float bf2f(unsigned short h) {
  return __uint_as_float((unsigned)h << 16);
}
__device__ __forceinline__ f32x4 splat4(float x) { return (f32x4){x, x, x, x}; }

// ---------------------------------------------------------------------------
// CSR row offsets, edge-parallel run writes (each rs[i] written exactly once).
// ---------------------------------------------------------------------------
__global__ void row_offsets_kernel(const int* __restrict__ dst, int n_edge,
                                   int* __restrict__ rs, int n_dst) {
  int e = blockIdx.x * blockDim.x + threadIdx.x;
  if (e >= n_edge) return;
  int d = dst[e];
  int dprev = (e == 0) ? -1 : dst[e - 1];
  for (int i = dprev + 1; i <= d; ++i) rs[i] = e;
  if (e == n_edge - 1)
    for (int i = d + 1; i <= n_dst; ++i) rs[i] = n_edge;
}

// ---------------------------------------------------------------------------
// One-time W prep: W[256][128] fp32 -> Wt[128][256] fp16, k permuted to MFMA
// slot order: pos(k) s.t. slot (kb,j) holds k = kb*4 + (j&3) + 16*(j>>2).
// ---------------------------------------------------------------------------
__global__ __launch_bounds__(256) void wt_prep_kernel(
    const float* __restrict__ W, _Float16* __restrict__ Wt) {
  int tid = blockIdx.x * blockDim.x + threadIdx.x;
  if (tid >= D_IN * D_H) return;
  int n = tid & 127, k = tid >> 7;
  float x = W[(size_t)k * D_H + n];
  int kk = k & 31, kbase = k & ~31;
  int pos = (kk < 16) ? ((kk >> 2) * 8 + (kk & 3))
                      : (((kk - 16) >> 2) * 8 + 4 + (kk & 3));
  Wt[(size_t)n * D_IN + kbase + pos] = (_Float16)x;
}

// ---------------------------------------------------------------------------
// Stage one K-step tile (A fp32 128x32 swizzled + B fp16 128x32) into LDS
// entirely via global_load_lds DMA. 6 gll instructions per wave.
// ---------------------------------------------------------------------------
__device__ __forceinline__ void stage_tile(
    const float* __restrict__ A, const _Float16* __restrict__ Wt,
    int m0, int M, int k0, int wave, int lane, float* Af, _Float16* Bf) {
#pragma unroll
  for (int i = 0; i < 4; ++i) {
    int rloc = wave * 32 + i * 8 + (lane >> 3);
    int gr = m0 + rloc; if (gr >= M) gr = M - 1;       // clamp; rows never stored
    int u = (lane & 7) ^ (rloc & 7);
    const float* src = A + (size_t)gr * D_IN + k0 + u * 4;
    char* dstb = (char*)Af + (size_t)(wave * 32 + i * 8) * 128;  // wave-uniform
    __builtin_amdgcn_global_load_lds(
        (const __attribute__((address_space(1))) unsigned int*)src,
        (__attribute__((address_space(3))) unsigned int*)dstb, 16, 0, 0);
  }
  // B: fp16 row = 64B; lane l -> row base+(l>>2), 16B unit l&3 (linear).
#pragma unroll
  for (int i = 0; i < 2; ++i) {
    int row = wave * 32 + i * 16 + (lane >> 2);
    int ch = lane & 3;
    const _Float16* srch = Wt + (size_t)row * D_IN + k0 + ch * 8;
    char* dsth = (char*)Bf + (size_t)(wave * 32 + i * 16) * 64;
    __builtin_amdgcn_global_load_lds(
        (const __attribute__((address_space(1))) unsigned int*)srch,
        (__attribute__((address_space(3))) unsigned int*)dsth, 16, 0, 0);
  }
}

// ---------------------------------------------------------------------------
// FUSED fp16 projections + FUSED SCORES (r21-exact GEMM, banked at ~94us).
// Triple-buffer depth-2 counted-vmcnt pipeline.
// C/D layout (verified m89): col = lane&15, row = (lane>>4)*4 + reg.
// ---------------------------------------------------------------------------
__global__ __launch_bounds__(256) void gemm_fused_kernel(
    const float* __restrict__ Au, const float* __restrict__ Ai,
    const _Float16* __restrict__ WtU, const _Float16* __restrict__ WtI,
    const float* __restrict__ bu, const float* __restrict__ bi,
    const float* __restrict__ aUdst, const float* __restrict__ aUsrc,
    const float* __restrict__ aIdst,
    float* __restrict__ sUdst, float* __restrict__ sIsrc,
    float* __restrict__ sIdst,
    unsigned short* __restrict__ CiBf, int nbu) {
  __shared__ float Af[3][128 * 32];                     // 3 x 16KB
  __shared__ _Float16 Bfs[3][128 * 32];                 // 3 x 8KB  (total 72KB)
  const bool isU = (int)blockIdx.x < nbu;
  const float* A = isU ? Au : Ai;
  const _Float16* Wt = isU ? WtU : WtI;
  const float* bias = isU ? bu : bi;
  const int M = isU ? N_USER : N_ITEM;
  const int m0 = (isU ? (int)blockIdx.x : (int)blockIdx.x - nbu) * 128;

  const int t = threadIdx.x;
  const int wave = t >> 6, lane = t & 63;
  const int l15 = lane & 15, kb = lane >> 4;

  f32x4 acc[2][8];
#pragma unroll
  for (int mf = 0; mf < 2; ++mf)
#pragma unroll
    for (int nf = 0; nf < 8; ++nf) acc[mf][nf] = (f32x4){0.f, 0.f, 0.f, 0.f};

  stage_tile(A, Wt, m0, M, 0, wave, lane, Af[0], Bfs[0]);
  stage_tile(A, Wt, m0, M, 32, wave, lane, Af[1], Bfs[1]);

#pragma unroll
  for (int ts = 0; ts < 8; ++ts) {
    const int cur = ts % 3;
    if (ts + 2 < 8) {                                  // prefetch tile ts+2
      stage_tile(A, Wt, m0, M, (ts + 2) * 32, wave, lane,
                 Af[(ts + 2) % 3], Bfs[(ts + 2) % 3]);
      asm volatile("s_waitcnt vmcnt(12)" ::: "memory"); // ts done; ts+1,ts+2 fly
    } else if (ts == 6) {
      asm volatile("s_waitcnt vmcnt(6)" ::: "memory");  // ts=6 done; 7 in flight
    } else {
      asm volatile("s_waitcnt vmcnt(0)" ::: "memory");  // final tile: drain all
    }
    __builtin_amdgcn_sched_barrier(0);                 // rule #18 fence
    __builtin_amdgcn_s_barrier();                      // all waves' tile ts ready

    half8v ah[2];
#pragma unroll
    for (int mf = 0; mf < 2; ++mf) {
      int row = wave * 32 + mf * 16 + l15;
      int u0 = kb ^ (row & 7);
      int u1 = (kb + 4) ^ (row & 7);
      float4 f0 = *(const float4*)((const char*)Af[cur] + (size_t)row * 128 + u0 * 16);
      float4 f1 = *(const float4*)((const char*)Af[cur] + (size_t)row * 128 + u1 * 16);
      const float e[8] = {f0.x, f0.y, f0.z, f0.w, f1.x, f1.y, f1.z, f1.w};
#pragma unroll
      for (int j = 0; j < 8; ++j) ah[mf][j] = (_Float16)e[j];
    }
#pragma unroll
    for (int nf = 0; nf < 8; ++nf) {
      half8v bh = *(const half8v*)((const char*)Bfs[cur] + (size_t)(nf * 16 + l15) * 64 + kb * 16);
#pragma unroll
      for (int mf = 0; mf < 2; ++mf)
        acc[mf][nf] = __builtin_amdgcn_mfma_f32_16x16x32_f16(ah[mf], bh, acc[mf][nf], 0, 0, 0);
    }
    __builtin_amdgcn_s_barrier();   // readers done before buf reuse (no drain)
  }

  // ---- epilogue: bf16 C (item) + fused scores ----
  if (!isU) {
#pragma unroll
    for (int nf = 0; nf < 8; ++nf) {
      float b8 = bias[nf * 16 + l15];
#pragma unroll
      for (int mf = 0; mf < 2; ++mf) {
#pragma unroll
        for (int r = 0; r < 4; ++r) {
          int grow = m0 + wave * 32 + mf * 16 + kb * 4 + r;
          if (grow < M)
            CiBf[(size_t)grow * D_H + nf * 16 + l15] = f2bf(acc[mf][nf][r] + b8);
        }
      }
    }
  }
  const float* a0 = isU ? aUdst : aUsrc;
  float* s0 = isU ? sUdst : sIsrc;
#pragma unroll
  for (int h = 0; h < HEADS; ++h) {
    float a0v[8], bd0 = 0.f;
#pragma unroll
    for (int nf = 0; nf < 8; ++nf) {
      a0v[nf] = a0[h * D_H + nf * 16 + l15];
      bd0 = fmaf(bias[nf * 16 + l15], a0v[nf], bd0);
    }
#pragma unroll
    for (int mf = 0; mf < 2; ++mf) {
#pragma unroll
      for (int r = 0; r < 4; ++r) {
        float p = bd0;
#pragma unroll
        for (int nf = 0; nf < 8; ++nf) p = fmaf(acc[mf][nf][r], a0v[nf], p);
        p += __shfl_xor(p, 1); p += __shfl_xor(p, 2);
        p += __shfl_xor(p, 4); p += __shfl_xor(p, 8);
        int grow = m0 + wave * 32 + mf * 16 + kb * 4 + r;
        if (l15 == 0 && grow < M) s0[grow * HEADS + h] = p;
      }
    }
  }
  if (!isU) {
#pragma unroll
    for (int h = 0; h < HEADS; ++h) {
      float a1v[8], bd1 = 0.f;
#pragma unroll
      for (int nf = 0; nf < 8; ++nf) {
        a1v[nf] = aIdst[h * D_H + nf * 16 + l15];
        bd1 = fmaf(bias[nf * 16 + l15], a1v[nf], bd1);
      }
#pragma unroll
      for (int mf = 0; mf < 2; ++mf) {
#pragma unroll
        for (int r = 0; r < 4; ++r) {
          float p = bd1;
#pragma unroll
          for (int nf = 0; nf < 8; ++nf) p = fmaf(acc[mf][nf][r], a1v[nf], p);
          p += __shfl_xor(p, 1); p += __shfl_xor(p, 2);
          p += __shfl_xor(p, 4); p += __shfl_xor(p, 8);
          int grow = m0 + wave * 32 + mf * 16 + kb * 4 + r;
          if (l15 == 0 && grow < M) sIdst[grow * HEADS + h] = p;
        }
      }
    }
  }
}

// ---------------------------------------------------------------------------
// Weighted gather-sum with inline edge weights (r18/r21-exact, measured best).
// 2 dst/wave, bf16 gather rows; den lane-uniform (no reductions).
// ---------------------------------------------------------------------------
__global__ __launch_bounds__(256) void attend_sum_kernel(
    const unsigned short* __restrict__ h_src, const float* __restrict__ s_src,
    const float* __restrict__ s_dst, const int* __restrict__ src_idx,
    const int* __restrict__ rs, float* __restrict__ out,
    unsigned short* __restrict__ out_bf, int n_dst,
    const float* __restrict__ a_next, float* __restrict__ s_out) {
  int gw = (blockIdx.x * blockDim.x + threadIdx.x) >> 6;   // global wave id
  int lane = threadIdx.x & 63;
  int half = lane >> 5;
  int ll = lane & 31;                // dim group: dims [ll*4, ll*4+4)
  int wid = gw * 2 + half;           // this half's dst node
  if (wid >= n_dst) return;
  int e0 = rs[wid], e1 = rs[wid + 1];
  f32x4 sd = *(const f32x4*)&s_dst[(size_t)wid * HEADS];

#define EDGE_W(sv, wv) {                                                    \
    f32x4 v_ = sv + sd;                                                     \
    v_.x = (v_.x >= 0.f) ? v_.x : 0.2f * v_.x;                              \
    v_.y = (v_.y >= 0.f) ? v_.y : 0.2f * v_.y;                              \
    v_.z = (v_.z >= 0.f) ? v_.z : 0.2f * v_.z;                              \
    v_.w = (v_.w >= 0.f) ? v_.w : 0.2f * v_.w;                              \
    wv = (f32x4){__expf(v_.x), __expf(v_.y), __expf(v_.z), __expf(v_.w)};   \
  }

  f32x4 acc0 = {0, 0, 0, 0}, acc1 = acc0, acc2 = acc0, acc3 = acc0;
  f32x4 den = {0, 0, 0, 0};

  int base = e0;
  for (; base + 2 <= e1; base += 2) {
    int sA = src_idx[base], sB = src_idx[base + 1];
    ushort4 gA = *(const ushort4*)&h_src[(size_t)sA * D_H + ll * 4];
    ushort4 gB = *(const ushort4*)&h_src[(size_t)sB * D_H + ll * 4];
    f32x4 svA = *(const f32x4*)&s_src[(size_t)sA * HEADS];
    f32x4 svB = *(const f32x4*)&s_src[(size_t)sB * HEADS];
    f32x4 hA = {bf2f(gA.x), bf2f(gA.y), bf2f(gA.z), bf2f(gA.w)};
    f32x4 hB = {bf2f(gB.x), bf2f(gB.y), bf2f(gB.z), bf2f(gB.w)};
    f32x4 wA, wB;
    EDGE_W(svA, wA); EDGE_W(svB, wB);
    den += wA; den += wB;
    acc0 = __builtin_elementwise_fma(splat4(wA.x), hA, acc0);
    acc1 = __builtin_elementwise_fma(splat4(wA.y), hA, acc1);
    acc2 = __builtin_elementwise_fma(splat4(wA.z), hA, acc2);
    acc3 = __builtin_elementwise_fma(splat4(wA.w), hA, acc3);
    acc0 = __builtin_elementwise_fma(splat4(wB.x), hB, acc0);
    acc1 = __builtin_elementwise_fma(splat4(wB.y), hB, acc1);
    acc2 = __builtin_elementwise_fma(splat4(wB.z), hB, acc2);
    acc3 = __builtin_elementwise_fma(splat4(wB.w), hB, acc3);
  }
  if (base < e1) {
    int s = src_idx[base];
    ushort4 gv = *(const ushort4*)&h_src[(size_t)s * D_H + ll * 4];
    f32x4 sv = *(const f32x4*)&s_src[(size_t)s * HEADS];
    f32x4 hv = {bf2f(gv.x), bf2f(gv.y), bf2f(gv.z), bf2f(gv.w)};
    f32x4 wv;
    EDGE_W(sv, wv);
    den += wv;
    acc0 = __builtin_elementwise_fma(splat4(wv.x), hv, acc0);
    acc1 = __builtin_elementwise_fma(splat4(wv.y), hv, acc1);
    acc2 = __builtin_elementwise_fma(splat4(wv.z), hv, acc2);
    acc3 = __builtin_elementwise_fma(splat4(wv.w), hv, acc3);
  }
#undef EDGE_W

  float rA = den.x > 0.f ? __builtin_amdgcn_rcpf(den.x) : 0.f;
  float rB = den.y > 0.f ? __builtin_amdgcn_rcpf(den.y) : 0.f;
  float rC = den.z > 0.f ? __builtin_amdgcn_rcpf(den.z) : 0.f;
  float rD = den.w > 0.f ? __builtin_amdgcn_rcpf(den.w) : 0.f;
  acc0 *= splat4(rA); acc1 *= splat4(rB); acc2 *= splat4(rC); acc3 *= splat4(rD);
#define ELU4(a) \
  a.x = (a.x > 0.f) ? a.x : (__expf(a.x) - 1.f); \
  a.y = (a.y > 0.f) ? a.y : (__expf(a.y) - 1.f); \
  a.z = (a.z > 0.f) ? a.z : (__expf(a.z) - 1.f); \
  a.w = (a.w > 0.f) ? a.w : (__expf(a.w) - 1.f);
  ELU4(acc0) ELU4(acc1) ELU4(acc2) ELU4(acc3)
#undef ELU4
  f32x4 o = (acc0 + acc1 + acc2 + acc3) * splat4(0.25f);
  *(f32x4*)&out[(size_t)wid * D_H + ll * 4] = o;
  if (out_bf) {
    ushort4 ob = {f2bf(o.x), f2bf(o.y), f2bf(o.z), f2bf(o.w)};
    *(ushort4*)&out_bf[(size_t)wid * D_H + ll * 4] = ob;
  }

  if (s_out) {
#pragma unroll
    for (int h = 0; h < HEADS; ++h) {
      const float* ah = &a_next[h * D_H + ll * 4];
      float p = o.x * ah[0] + o.y * ah[1] + o.z * ah[2] + o.w * ah[3];
#pragma unroll
      for (int off = 16; off; off >>= 1) p += __shfl_xor(p, off);
      if (ll == 0) s_out[wid * HEADS + h] = p;
    }
  }
}

// ---------------------------------------------------------------------------
extern "C" void kernel_launch(void* const* d_in, const int* in_sizes, int n_in,
                              void* d_out, int out_size, void* d_ws, size_t ws_size,
                              hipStream_t stream) {
  const float* h_user     = (const float*)d_in[0];
  const float* h_item     = (const float*)d_in[1];
  const float* w_user     = (const float*)d_in[2];
  const float* b_user     = (const float*)d_in[3];
  const float* w_item     = (const float*)d_in[4];
  const float* b_item     = (const float*)d_in[5];
  const float* a_user_src = (const float*)d_in[6];
  const float* a_user_dst = (const float*)d_in[7];
  const float* a_item_src = (const float*)d_in[8];
  const float* a_item_dst = (const float*)d_in[9];
  const int* i2u_src = (const int*)d_in[10];
  const int* i2u_dst = (const int*)d_in[11];
  const int* u2i_src = (const int*)d_in[12];
  const int* u2i_dst = (const int*)d_in[13];

  float* out_user = (float*)d_out;                       // hu_new (N_USER,128)
  float* out_item = out_user + (size_t)N_USER * D_H;     // hi_new (N_ITEM,128)

  // workspace layout
  float* base_f  = (float*)d_ws;
  unsigned short* ou_bf = (unsigned short*)base_f;       // (N_USER,128) bf16 25.6MB
  float* s_i_src = (float*)(ou_bf + (size_t)N_USER * D_H);  // (N_ITEM,4)
  float* s_i_dst = s_i_src + (size_t)N_ITEM * HEADS;     // (N_ITEM,4)
  float* s_u_dst = s_i_dst + (size_t)N_ITEM * HEADS;     // (N_USER,4)
  float* s_un    = s_u_dst + (size_t)N_USER * HEADS;     // (N_USER,4)
  int* user_rs = (int*)(s_un + (size_t)N_USER * HEADS);  // N_USER+1
  int* item_rs = user_rs + (N_USER + 1);                 // N_ITEM+1
  _Float16* wtu = (_Float16*)
      (((uintptr_t)(item_rs + N_ITEM + 1) + 15) & ~(uintptr_t)15);
  _Float16* wti = wtu + (size_t)D_IN * D_H;              // 64KB each
  unsigned short* hi_bf = (unsigned short*)(wti + (size_t)D_IN * D_H);  // 12.8MB

  // CSR offsets (edge-parallel run writes)
  hipLaunchKernelGGL(row_offsets_kernel, dim3((N_EDGE + 255) / 256), dim3(256), 0,
                     stream, i2u_dst, N_EDGE, user_rs, N_USER);
  hipLaunchKernelGGL(row_offsets_kernel, dim3((N_EDGE + 255) / 256), dim3(256), 0,
                     stream, u2i_dst, N_EDGE, item_rs, N_ITEM);

  // W prep + FUSED fp16 projections+scores (one dispatch, 1173 blocks)
  hipLaunchKernelGGL(wt_prep_kernel, dim3(D_IN * D_H / 256), dim3(256), 0, stream,
                     w_user, wtu);
  hipLaunchKernelGGL(wt_prep_kernel, dim3(D_IN * D_H / 256), dim3(256), 0, stream,
                     w_item, wti);
  const int nbu = (N_USER + 127) / 128;                  // 782
  const int nbi = (N_ITEM + 127) / 128;                  // 391
  hipLaunchKernelGGL(gemm_fused_kernel, dim3(nbu + nbi), dim3(256), 0, stream,
                     h_user, h_item, wtu, wti, b_user, b_item,
                     a_user_dst, a_user_src, a_item_dst,
                     s_u_dst, s_i_src, s_i_dst, hi_bf, nbu);

  // ---- layer 1: items -> users ----  (bf16 gather; inline edge weights)
  hipLaunchKernelGGL(attend_sum_kernel, dim3((N_USER + 7) / 8), dim3(256), 0, stream,
                     hi_bf, s_i_src, s_u_dst, i2u_src, user_rs,
                     out_user, ou_bf, N_USER, a_item_src, s_un);

  // ---- layer 2: updated users -> items ----
  hipLaunchKernelGGL(attend_sum_kernel, dim3((N_ITEM + 7) / 8), dim3(256), 0, stream,
                     ou_bf, s_un, s_i_dst, u2i_src, item_rs,
                     out_item, (unsigned short*)nullptr, N_ITEM,
                     (const float*)nullptr, (float*)nullptr);
}